// Round 1
// 401.884 us; speedup vs baseline: 1.0463x; 1.0463x over previous
//
#include <hip/hip_runtime.h>

#define B_ 1024
#define N_ 24
#define CI_ 2
#define CO_ 2
#define E_ 256
#define H_ 4
#define DH_ 64

typedef __bf16 v8bf __attribute__((ext_vector_type(8)));
typedef float v4f __attribute__((ext_vector_type(4)));

union Frag {
    uint4 u;
    v8bf v;
};

__device__ __forceinline__ v4f mfma16(v8bf a, v8bf b, v4f c) {
    return __builtin_amdgcn_mfma_f32_16x16x32_bf16(a, b, c, 0, 0, 0);
}

// load 8 consecutive f32 and round to 8 bf16 (for MFMA A/B fragments)
__device__ __forceinline__ v8bf cvt8(const float* __restrict__ p) {
    float4 a = *(const float4*)p;
    float4 b = *(const float4*)(p + 4);
    v8bf r;
    r[0] = (__bf16)a.x; r[1] = (__bf16)a.y; r[2] = (__bf16)a.z; r[3] = (__bf16)a.w;
    r[4] = (__bf16)b.x; r[5] = (__bf16)b.y; r[6] = (__bf16)b.z; r[7] = (__bf16)b.w;
    return r;
}

// byte offset into a [24][256] bf16 tile with XOR bank-swizzle (T2 pattern):
// row stride 512B == 0 mod 32 banks -> 16-way conflict without swizzle.
__device__ __forceinline__ int qk_off(int row, int col) {
    return ((row << 9) + (col << 1)) ^ ((row & 7) << 4);
}

// ---------------------------------------------------------------------------
// Kernel T: downcast f32->bf16 + transpose last-two-dims of kernel tensor
// (96 mats of 256x256) and Wq/Wk/Wv (3 mats) so MFMA B-fragments become
// contiguous 16B bf16 loads.
// ---------------------------------------------------------------------------
__global__ __launch_bounds__(256) void ktrans(
    const float* __restrict__ kern, const float* __restrict__ wq,
    const float* __restrict__ wk, const float* __restrict__ wv,
    __bf16* __restrict__ wt, __bf16* __restrict__ kt) {
    __shared__ __bf16 t[64][65];
    const int blk = blockIdx.x;
    const int mat = blk >> 4, tile = blk & 15;
    const int r0 = (tile >> 2) * 64, c0 = (tile & 3) * 64;
    const float* src;
    __bf16* dst;
    if (mat < 96) {
        src = kern + (size_t)mat * 65536;
        dst = kt + (size_t)mat * 65536;
    } else {
        int p = mat - 96;
        src = (p == 0) ? wq : (p == 1) ? wk : wv;
        dst = wt + (size_t)p * 65536;
    }
    const int tid = threadIdx.x;
#pragma unroll
    for (int k = 0; k < 16; ++k) {
        int idx = k * 256 + tid;
        int e = idx >> 6, f = idx & 63;
        t[f][e] = (__bf16)src[(size_t)(r0 + e) * 256 + c0 + f];
    }
    __syncthreads();
#pragma unroll
    for (int k = 0; k < 16; ++k) {
        int idx = k * 256 + tid;
        int f = idx >> 6, e = idx & 63;
        dst[(size_t)(c0 + f) * 256 + r0 + e] = t[f][e];
    }
}

// ---------------------------------------------------------------------------
// Kernel A: per-(b,seq) fused attention. 256 threads = 4 waves (1 per head).
// Grid = B*CI = 2048 blocks; LDS = 36 KB -> 4 blocks/CU (16 waves/CU), vs the
// previous per-b variant's 84 KB -> 1 block/CU (8 waves/CU).
// Phase 1: QKV = x@W + b via MFMA (24 rows padded to 32 = 2 row-frags; each
//          wave owns 4 col-frags of 16). Store Q,K (swizzled) and V^T to LDS.
// Phase 2: scores = QK^T/8 via MFMA (head = wave); softmax in-register with
//          16-lane shuffles; then P -> LDS *aliased over sQ* (extra barrier).
// Phase 3: ctx = P@V via MFMA; store bf16 ctx[b][i][n][f].
// ---------------------------------------------------------------------------
__global__ __launch_bounds__(256) void kattn(
    const float* __restrict__ feat, const __bf16* __restrict__ wt,
    const float* __restrict__ bq, const float* __restrict__ bk,
    const float* __restrict__ bv, __bf16* __restrict__ ctx) {
    __shared__ __bf16 sQP[24 * 256];  // 12 KB: sQ (swizzled); later sP[4][24][56]
    __shared__ __bf16 sK[24 * 256];   // 12 KB (swizzled)
    __shared__ __bf16 sVT[E_][N_];    // 12 KB (V transposed: [f][kn])

    const int bs = blockIdx.x;  // 0..2047
    const int b = bs >> 1, seq = bs & 1;
    const int tid = threadIdx.x;
    const int wave = tid >> 6, lane = tid & 63;
    const int quad = lane >> 4, l16 = lane & 15;
    const float* pb[3] = {bq, bk, bv};

    const uint4 zero4 = make_uint4(0u, 0u, 0u, 0u);
    const v4f zf = {0.f, 0.f, 0.f, 0.f};

    // ---------------- Phase 1: QKV projections ----------------
#pragma unroll
    for (int p = 0; p < 3; ++p) {
        const __bf16* W = wt + (size_t)p * 65536;
        v4f acc[2][4];
#pragma unroll
        for (int rf = 0; rf < 2; ++rf)
#pragma unroll
            for (int c = 0; c < 4; ++c) acc[rf][c] = zf;

#pragma unroll
        for (int ks = 0; ks < 8; ++ks) {
            const int kb = ks * 32 + quad * 8;
            Frag a[2], bb[4];
#pragma unroll
            for (int rf = 0; rf < 2; ++rf) {
                const int n = rf * 16 + l16;
                if (n < N_)
                    a[rf].v = cvt8(feat + ((size_t)((b * N_ + n) * CI_ + seq)) * E_ + kb);
                else
                    a[rf].u = zero4;
            }
#pragma unroll
            for (int c = 0; c < 4; ++c) {
                const int f0 = wave * 64 + c * 16;
                bb[c].u = *(const uint4*)(W + (size_t)(f0 + l16) * E_ + kb);
            }
#pragma unroll
            for (int rf = 0; rf < 2; ++rf)
#pragma unroll
                for (int c = 0; c < 4; ++c)
                    acc[rf][c] = mfma16(a[rf].v, bb[c].v, acc[rf][c]);
        }
        // store to LDS (+bias)
#pragma unroll
        for (int c = 0; c < 4; ++c) {
            const int f = wave * 64 + c * 16 + l16;
            const float biasf = pb[p][f];
#pragma unroll
            for (int rf = 0; rf < 2; ++rf) {
#pragma unroll
                for (int r = 0; r < 4; ++r) {
                    const int row = rf * 16 + quad * 4 + r;
                    if (row < N_) {
                        const float v = acc[rf][c][r] + biasf;
                        if (p == 0)
                            *(__bf16*)((char*)sQP + qk_off(row, f)) = (__bf16)v;
                        else if (p == 1)
                            *(__bf16*)((char*)sK + qk_off(row, f)) = (__bf16)v;
                        else
                            sVT[f][row] = (__bf16)v;
                    }
                }
            }
        }
    }
    __syncthreads();

    // ---------------- Phase 2: scores + softmax (head = wave) ----------
    const int h = wave;
    v4f sc[2][2];
#pragma unroll
    for (int mt = 0; mt < 2; ++mt)
#pragma unroll
        for (int nt = 0; nt < 2; ++nt) sc[mt][nt] = zf;

#pragma unroll
    for (int ks = 0; ks < 2; ++ks) {
        const int d0 = h * DH_ + ks * 32 + quad * 8;
        Frag a[2], bb[2];
#pragma unroll
        for (int mt = 0; mt < 2; ++mt) {
            const int qn = mt * 16 + l16;
            a[mt].u = (qn < N_) ? *(const uint4*)((const char*)sQP + qk_off(qn, d0)) : zero4;
        }
#pragma unroll
        for (int nt = 0; nt < 2; ++nt) {
            const int kn = nt * 16 + l16;
            bb[nt].u = (kn < N_) ? *(const uint4*)((const char*)sK + qk_off(kn, d0)) : zero4;
        }
#pragma unroll
        for (int mt = 0; mt < 2; ++mt)
#pragma unroll
            for (int nt = 0; nt < 2; ++nt)
                sc[mt][nt] = mfma16(a[mt].v, bb[nt].v, sc[mt][nt]);
    }

    const float scale = 0.125f;  // 1/sqrt(64)
    float pr0[2][4], pr1[2][4];
#pragma unroll
    for (int mt = 0; mt < 2; ++mt) {
#pragma unroll
        for (int r = 0; r < 4; ++r) {
            const float v0 = sc[mt][0][r] * scale;
            const float v1 = (l16 < 8) ? sc[mt][1][r] * scale : -3.0e38f;  // kn=16+l16 >= 24 masked
            float mx = fmaxf(v0, v1);
#pragma unroll
            for (int m = 1; m < 16; m <<= 1) mx = fmaxf(mx, __shfl_xor(mx, m));
            const float e0 = __expf(v0 - mx);
            const float e1 = (l16 < 8) ? __expf(v1 - mx) : 0.f;
            float s = e0 + e1;
#pragma unroll
            for (int m = 1; m < 16; m <<= 1) s += __shfl_xor(s, m);
            const float inv = 1.f / s;
            pr0[mt][r] = e0 * inv;
            pr1[mt][r] = e1 * inv;
        }
    }
    __syncthreads();  // all sQ reads done -> safe to overwrite with sP

    // sP[4][24][56] aliased over sQP (row stride 56 elems = 112 B: 16B-aligned,
    // 28 dwords mod 32 -> 2-way conflicts only)
    __bf16* sP = sQP;
#pragma unroll
    for (int mt = 0; mt < 2; ++mt) {
#pragma unroll
        for (int r = 0; r < 4; ++r) {
            const int qn = mt * 16 + quad * 4 + r;
            if (qn < N_) {
                sP[(h * N_ + qn) * 56 + l16] = (__bf16)pr0[mt][r];
                sP[(h * N_ + qn) * 56 + 16 + l16] = (__bf16)pr1[mt][r];
            }
        }
    }
    __syncthreads();

    // ---------------- Phase 3: ctx = P @ V ----------------
    Frag pa[2], vb[4];
#pragma unroll
    for (int mt = 0; mt < 2; ++mt) {
        const int qn = mt * 16 + l16;
        pa[mt].u = (qn < N_) ? *(const uint4*)(&sP[(h * N_ + qn) * 56 + quad * 8]) : zero4;
    }
#pragma unroll
    for (int nt = 0; nt < 4; ++nt) {
        // kn = quad*8 + j ; quad==3 -> kn in [24,32) : zero (P there is 0 anyway)
        vb[nt].u = (quad < 3) ? *(const uint4*)(&sVT[h * DH_ + nt * 16 + l16][quad * 8]) : zero4;
    }
#pragma unroll
    for (int mt = 0; mt < 2; ++mt) {
#pragma unroll
        for (int nt = 0; nt < 4; ++nt) {
            v4f c0 = zf;
            c0 = mfma16(pa[mt].v, vb[nt].v, c0);
#pragma unroll
            for (int r = 0; r < 4; ++r) {
                const int qn = mt * 16 + quad * 4 + r;
                if (qn < N_) {
                    const int f = h * DH_ + nt * 16 + l16;
                    ctx[((size_t)((b * CI_ + seq) * N_ + qn)) * E_ + f] = (__bf16)c0[r];
                }
            }
        }
    }
}

// ---------------------------------------------------------------------------
// Kernel P: pkq[b,n,o,f] = sum_i ctx[b,i,n,f] * (feat[b,n,i,:] @ K[o,i,n,:,f])
//           + bias + residual, then LayerNorm over f.
// Grid (16, 24, 2): 64 b-rows x 256 f-cols per block; wave w owns rows
// [16w,16w+16). K-contraction E=256 via MFMA; per-i result scaled by ctx.
// ---------------------------------------------------------------------------
__global__ __launch_bounds__(256) void kpkln(
    const float* __restrict__ feat, const __bf16* __restrict__ kt,
    const __bf16* __restrict__ ctx, const float* __restrict__ bias,
    const float* __restrict__ gamma, const float* __restrict__ beta,
    float* __restrict__ out) {
    const int bt = blockIdx.x;  // 0..15
    const int n = blockIdx.y;   // 0..23
    const int o = blockIdx.z;   // 0..1
    const int tid = threadIdx.x;
    const int wave = tid >> 6, lane = tid & 63;
    const int quad = lane >> 4, l16 = lane & 15;
    const int b0 = bt * 64 + wave * 16;

    const v4f zf = {0.f, 0.f, 0.f, 0.f};
    float accf[16][4];
#pragma unroll
    for (int cf = 0; cf < 16; ++cf)
#pragma unroll
        for (int r = 0; r < 4; ++r) accf[cf][r] = 0.f;

#pragma unroll
    for (int i = 0; i < CI_; ++i) {
        v4f g[16];
#pragma unroll
        for (int cf = 0; cf < 16; ++cf) g[cf] = zf;

        const float* A = feat + ((size_t)((b0 + l16) * N_ + n) * CI_ + i) * E_;
        const __bf16* Bm = kt + ((size_t)((o * CI_ + i) * N_ + n)) * 65536;
#pragma unroll
        for (int ks = 0; ks < 8; ++ks) {
            const int kb = ks * 32 + quad * 8;
            Frag a;
            a.v = cvt8(A + kb);
#pragma unroll
            for (int cf = 0; cf < 16; ++cf) {
                Frag bb;
                bb.u = *(const uint4*)(Bm + (size_t)(cf * 16 + l16) * E_ + kb);
                g[cf] = mfma16(a.v, bb.v, g[cf]);
            }
        }
        // scale by ctx and accumulate over i
#pragma unroll
        for (int cf = 0; cf < 16; ++cf) {
            const int f = cf * 16 + l16;
#pragma unroll
            for (int r = 0; r < 4; ++r) {
                const int brow = b0 + quad * 4 + r;
                const float cv = (float)ctx[((size_t)((brow * CI_ + i) * N_ + n)) * E_ + f];
                accf[cf][r] += cv * g[cf][r];
            }
        }
    }

    // epilogue: +bias +residual, LayerNorm over f (256), store f32
    const float bias_no = bias[n * CO_ + o];
#pragma unroll
    for (int r = 0; r < 4; ++r) {
        const int brow = b0 + quad * 4 + r;
        const float* resid = feat + ((size_t)((brow * N_ + n) * CI_ + o)) * E_;
        float s = 0.f;
#pragma unroll
        for (int cf = 0; cf < 16; ++cf) {
            const float v = accf[cf][r] + bias_no + resid[cf * 16 + l16];
            accf[cf][r] = v;
            s += v;
        }
#pragma unroll
        for (int m = 1; m < 16; m <<= 1) s += __shfl_xor(s, m);
        const float mean = s * (1.f / 256.f);
        float s2 = 0.f;
#pragma unroll
        for (int cf = 0; cf < 16; ++cf) {
            const float d = accf[cf][r] - mean;
            s2 += d * d;
        }
#pragma unroll
        for (int m = 1; m < 16; m <<= 1) s2 += __shfl_xor(s2, m);
        const float rstd = rsqrtf(s2 * (1.f / 256.f) + 1e-12f);
        float* op = out + ((size_t)((brow * N_ + n) * CO_ + o)) * E_;
#pragma unroll
        for (int cf = 0; cf < 16; ++cf) {
            const int f = cf * 16 + l16;
            op[f] = (accf[cf][r] - mean) * rstd * gamma[f] + beta[f];
        }
    }
}

// ---------------------------------------------------------------------------
extern "C" void kernel_launch(void* const* d_in, const int* in_sizes, int n_in,
                              void* d_out, int out_size, void* d_ws, size_t ws_size,
                              hipStream_t stream) {
    const float* feat = (const float*)d_in[0];
    const float* kern = (const float*)d_in[1];
    const float* bias = (const float*)d_in[2];
    const float* wq = (const float*)d_in[3];
    const float* bq = (const float*)d_in[4];
    const float* wk = (const float*)d_in[5];
    const float* bk = (const float*)d_in[6];
    const float* wv = (const float*)d_in[7];
    const float* bv = (const float*)d_in[8];
    const float* gamma = (const float*)d_in[9];
    const float* beta = (const float*)d_in[10];

    __bf16* ws = (__bf16*)d_ws;
    __bf16* wt = ws;                        // 3 * 65536 bf16
    __bf16* kt = ws + (size_t)3 * 65536;    // 96 * 65536 bf16
    __bf16* ctx = kt + (size_t)96 * 65536;  // 2048 * 24 * 256 bf16
    float* out = (float*)d_out;

    hipLaunchKernelGGL(ktrans, dim3(99 * 16), dim3(256), 0, stream,
                       kern, wq, wk, wv, wt, kt);
    hipLaunchKernelGGL(kattn, dim3(B_ * CI_), dim3(256), 0, stream,
                       feat, wt, bq, bk, bv, ctx);
    hipLaunchKernelGGL(kpkln, dim3(16, N_, CO_), dim3(256), 0, stream,
                       feat, kt, ctx, bias, gamma, beta, out);
}

// Round 2
// 392.295 us; speedup vs baseline: 1.0719x; 1.0244x over previous
//
#include <hip/hip_runtime.h>

#define B_ 1024
#define N_ 24
#define CI_ 2
#define CO_ 2
#define E_ 256
#define H_ 4
#define DH_ 64

typedef __bf16 v8bf __attribute__((ext_vector_type(8)));
typedef float v4f __attribute__((ext_vector_type(4)));

union Frag {
    uint4 u;
    v8bf v;
};

union Pack4 {
    ushort4 u;
    __bf16 h[4];
};

__device__ __forceinline__ v4f mfma16(v8bf a, v8bf b, v4f c) {
    return __builtin_amdgcn_mfma_f32_16x16x32_bf16(a, b, c, 0, 0, 0);
}

// load 8 consecutive f32 and round to 8 bf16 (for MFMA A/B fragments)
__device__ __forceinline__ v8bf cvt8(const float* __restrict__ p) {
    float4 a = *(const float4*)p;
    float4 b = *(const float4*)(p + 4);
    v8bf r;
    r[0] = (__bf16)a.x; r[1] = (__bf16)a.y; r[2] = (__bf16)a.z; r[3] = (__bf16)a.w;
    r[4] = (__bf16)b.x; r[5] = (__bf16)b.y; r[6] = (__bf16)b.z; r[7] = (__bf16)b.w;
    return r;
}

// ---------------------------------------------------------------------------
// Kernel T: downcast f32->bf16 + transpose last-two-dims of kernel tensor
// (96 mats of 256x256) and Wq/Wk/Wv (3 mats) so MFMA B-fragments become
// contiguous 16B bf16 loads.
// ---------------------------------------------------------------------------
__global__ __launch_bounds__(256) void ktrans(
    const float* __restrict__ kern, const float* __restrict__ wq,
    const float* __restrict__ wk, const float* __restrict__ wv,
    __bf16* __restrict__ wt, __bf16* __restrict__ kt) {
    __shared__ __bf16 t[64][65];
    const int blk = blockIdx.x;
    const int mat = blk >> 4, tile = blk & 15;
    const int r0 = (tile >> 2) * 64, c0 = (tile & 3) * 64;
    const float* src;
    __bf16* dst;
    if (mat < 96) {
        src = kern + (size_t)mat * 65536;
        dst = kt + (size_t)mat * 65536;
    } else {
        int p = mat - 96;
        src = (p == 0) ? wq : (p == 1) ? wk : wv;
        dst = wt + (size_t)p * 65536;
    }
    const int tid = threadIdx.x;
#pragma unroll
    for (int k = 0; k < 16; ++k) {
        int idx = k * 256 + tid;
        int e = idx >> 6, f = idx & 63;
        t[f][e] = (__bf16)src[(size_t)(r0 + e) * 256 + c0 + f];
    }
    __syncthreads();
#pragma unroll
    for (int k = 0; k < 16; ++k) {
        int idx = k * 256 + tid;
        int f = idx >> 6, e = idx & 63;
        dst[(size_t)(c0 + f) * 256 + r0 + e] = t[f][e];
    }
}

// ---------------------------------------------------------------------------
// Kernel QKV: fused Q/K/V projection GEMM, one (b,seq) per block, wave = head.
// A-fragments (feat rows, f32->bf16) loaded ONCE per ks and reused for all
// three projections (they share the same A). Each wave only needs the 64
// W-columns of its own head. No LDS, no barriers.
// Outputs: gQ, gK row-major [bs][24][256]; gVT transposed [bs][256][24].
// ---------------------------------------------------------------------------
__global__ __launch_bounds__(256) void kqkv(
    const float* __restrict__ feat, const __bf16* __restrict__ wt,
    const float* __restrict__ bq, const float* __restrict__ bk,
    const float* __restrict__ bv,
    __bf16* __restrict__ gQ, __bf16* __restrict__ gK, __bf16* __restrict__ gVT) {
    const int bs = blockIdx.x;  // 0..2047
    const int b = bs >> 1, seq = bs & 1;
    const int tid = threadIdx.x;
    const int h = tid >> 6, lane = tid & 63;
    const int quad = lane >> 4, l16 = lane & 15;

    const uint4 zero4 = make_uint4(0u, 0u, 0u, 0u);
    const v4f zf = {0.f, 0.f, 0.f, 0.f};

    v4f acc[3][2][4];  // [m=q/k/v][row frag][col frag]
#pragma unroll
    for (int m = 0; m < 3; ++m)
#pragma unroll
        for (int rf = 0; rf < 2; ++rf)
#pragma unroll
            for (int c = 0; c < 4; ++c) acc[m][rf][c] = zf;

#pragma unroll
    for (int ks = 0; ks < 8; ++ks) {
        const int kb = ks * 32 + quad * 8;
        Frag a[2];
#pragma unroll
        for (int rf = 0; rf < 2; ++rf) {
            const int n = rf * 16 + l16;
            if (n < N_)
                a[rf].v = cvt8(feat + ((size_t)((b * N_ + n) * CI_ + seq)) * E_ + kb);
            else
                a[rf].u = zero4;
        }
#pragma unroll
        for (int m = 0; m < 3; ++m) {
            const __bf16* W = wt + (size_t)m * 65536;
#pragma unroll
            for (int c = 0; c < 4; ++c) {
                Frag bb;
                bb.u = *(const uint4*)(W + (size_t)(h * 64 + c * 16 + l16) * E_ + kb);
#pragma unroll
                for (int rf = 0; rf < 2; ++rf)
                    acc[m][rf][c] = mfma16(a[rf].v, bb.v, acc[m][rf][c]);
            }
        }
    }

    // epilogue: +bias, store Q,K row-major; V transposed (packed 8B stores)
#pragma unroll
    for (int c = 0; c < 4; ++c) {
        const int f = h * 64 + c * 16 + l16;
        const float bQ = bq[f], bK = bk[f], bV = bv[f];
#pragma unroll
        for (int rf = 0; rf < 2; ++rf) {
#pragma unroll
            for (int r = 0; r < 4; ++r) {
                const int row = rf * 16 + quad * 4 + r;
                if (row < N_) {
                    gQ[(size_t)(bs * N_ + row) * E_ + f] = (__bf16)(acc[0][rf][c][r] + bQ);
                    gK[(size_t)(bs * N_ + row) * E_ + f] = (__bf16)(acc[1][rf][c][r] + bK);
                }
            }
            const int kn0 = rf * 16 + quad * 4;
            if (kn0 < N_) {
                Pack4 p;
#pragma unroll
                for (int r = 0; r < 4; ++r) p.h[r] = (__bf16)(acc[2][rf][c][r] + bV);
                *(ushort4*)(gVT + (size_t)(bs * E_ + f) * N_ + kn0) = p.u;
            }
        }
    }
}

// ---------------------------------------------------------------------------
// Kernel A2: scores + softmax + PV. One (b,seq) per block, wave = head.
// No __syncthreads at all: the only LDS (P staging for the in-wave
// transpose) is wave-local. 16 MFMA + softmax per wave; waves fully
// independent -> deep latency hiding. QKV read from global (L3-resident).
// ---------------------------------------------------------------------------
__global__ __launch_bounds__(256) void kattn2(
    const __bf16* __restrict__ gQ, const __bf16* __restrict__ gK,
    const __bf16* __restrict__ gVT, __bf16* __restrict__ ctx) {
    __shared__ __bf16 sP[H_][N_][56];  // 10.5 KB, wave-local rows

    const int bs = blockIdx.x;  // 0..2047
    const int tid = threadIdx.x;
    const int h = tid >> 6, lane = tid & 63;
    const int quad = lane >> 4, l16 = lane & 15;

    const uint4 zero4 = make_uint4(0u, 0u, 0u, 0u);
    const v4f zf = {0.f, 0.f, 0.f, 0.f};

    // ---- scores = Q K^T / 8 ----
    v4f sc[2][2];
#pragma unroll
    for (int mt = 0; mt < 2; ++mt)
#pragma unroll
        for (int nt = 0; nt < 2; ++nt) sc[mt][nt] = zf;

#pragma unroll
    for (int ks = 0; ks < 2; ++ks) {
        const int d0 = h * DH_ + ks * 32 + quad * 8;
        Frag a[2], bb[2];
#pragma unroll
        for (int mt = 0; mt < 2; ++mt) {
            const int qn = mt * 16 + l16;
            a[mt].u = (qn < N_) ? *(const uint4*)(gQ + (size_t)(bs * N_ + qn) * E_ + d0) : zero4;
        }
#pragma unroll
        for (int nt = 0; nt < 2; ++nt) {
            const int kn = nt * 16 + l16;
            bb[nt].u = (kn < N_) ? *(const uint4*)(gK + (size_t)(bs * N_ + kn) * E_ + d0) : zero4;
        }
#pragma unroll
        for (int mt = 0; mt < 2; ++mt)
#pragma unroll
            for (int nt = 0; nt < 2; ++nt)
                sc[mt][nt] = mfma16(a[mt].v, bb[nt].v, sc[mt][nt]);
    }

    // ---- softmax (rows in-register, 16-lane shuffles) ----
    const float scale = 0.125f;  // 1/sqrt(64)
#pragma unroll
    for (int mt = 0; mt < 2; ++mt) {
#pragma unroll
        for (int r = 0; r < 4; ++r) {
            const int qn = mt * 16 + quad * 4 + r;
            const float v0 = sc[mt][0][r] * scale;
            const float v1 = (l16 < 8) ? sc[mt][1][r] * scale : -3.0e38f;  // kn>=24 masked
            float mx = fmaxf(v0, v1);
#pragma unroll
            for (int m = 1; m < 16; m <<= 1) mx = fmaxf(mx, __shfl_xor(mx, m));
            const float e0 = __expf(v0 - mx);
            const float e1 = (l16 < 8) ? __expf(v1 - mx) : 0.f;
            float s = e0 + e1;
#pragma unroll
            for (int m = 1; m < 16; m <<= 1) s += __shfl_xor(s, m);
            const float inv = 1.f / s;
            if (qn < N_) {
                sP[h][qn][l16] = (__bf16)(e0 * inv);
                sP[h][qn][16 + l16] = (__bf16)(e1 * inv);
            }
        }
    }
    // no barrier: sP[h] is wave-local; compiler inserts lgkmcnt waits

    // ---- ctx = P @ V ----
    Frag pa[2], vb[4];
#pragma unroll
    for (int mt = 0; mt < 2; ++mt) {
        const int qn = mt * 16 + l16;
        pa[mt].u = (qn < N_) ? *(const uint4*)(&sP[h][qn][quad * 8]) : zero4;
    }
#pragma unroll
    for (int nt = 0; nt < 4; ++nt) {
        const int f = h * DH_ + nt * 16 + l16;
        // kn = quad*8 + j ; quad==3 -> kn in [24,32): P there is exactly 0
        vb[nt].u = (quad < 3) ? *(const uint4*)(gVT + (size_t)(bs * E_ + f) * N_ + quad * 8) : zero4;
    }
#pragma unroll
    for (int mt = 0; mt < 2; ++mt) {
#pragma unroll
        for (int nt = 0; nt < 4; ++nt) {
            v4f c0 = zf;
            c0 = mfma16(pa[mt].v, vb[nt].v, c0);
#pragma unroll
            for (int r = 0; r < 4; ++r) {
                const int qn = mt * 16 + quad * 4 + r;
                if (qn < N_) {
                    const int f = h * DH_ + nt * 16 + l16;
                    ctx[((size_t)(bs * N_ + qn)) * E_ + f] = (__bf16)c0[r];
                }
            }
        }
    }
}

// ---------------------------------------------------------------------------
// Kernel P: pkq[b,n,o,f] = sum_i ctx[b,i,n,f] * (feat[b,n,i,:] @ K[o,i,n,:,f])
//           + bias + residual, then LayerNorm over f.
// Grid (16, 24, 2): 64 b-rows x 256 f-cols per block; wave w owns rows
// [16w,16w+16). K-contraction E=256 via MFMA; per-i result scaled by ctx.
// ---------------------------------------------------------------------------
__global__ __launch_bounds__(256) void kpkln(
    const float* __restrict__ feat, const __bf16* __restrict__ kt,
    const __bf16* __restrict__ ctx, const float* __restrict__ bias,
    const float* __restrict__ gamma, const float* __restrict__ beta,
    float* __restrict__ out) {
    const int bt = blockIdx.x;  // 0..15
    const int n = blockIdx.y;   // 0..23
    const int o = blockIdx.z;   // 0..1
    const int tid = threadIdx.x;
    const int wave = tid >> 6, lane = tid & 63;
    const int quad = lane >> 4, l16 = lane & 15;
    const int b0 = bt * 64 + wave * 16;

    const v4f zf = {0.f, 0.f, 0.f, 0.f};
    float accf[16][4];
#pragma unroll
    for (int cf = 0; cf < 16; ++cf)
#pragma unroll
        for (int r = 0; r < 4; ++r) accf[cf][r] = 0.f;

#pragma unroll
    for (int i = 0; i < CI_; ++i) {
        v4f g[16];
#pragma unroll
        for (int cf = 0; cf < 16; ++cf) g[cf] = zf;

        const float* A = feat + ((size_t)((b0 + l16) * N_ + n) * CI_ + i) * E_;
        const __bf16* Bm = kt + ((size_t)((o * CI_ + i) * N_ + n)) * 65536;
#pragma unroll
        for (int ks = 0; ks < 8; ++ks) {
            const int kb = ks * 32 + quad * 8;
            Frag a;
            a.v = cvt8(A + kb);
#pragma unroll
            for (int cf = 0; cf < 16; ++cf) {
                Frag bb;
                bb.u = *(const uint4*)(Bm + (size_t)(cf * 16 + l16) * E_ + kb);
                g[cf] = mfma16(a.v, bb.v, g[cf]);
            }
        }
        // scale by ctx and accumulate over i
#pragma unroll
        for (int cf = 0; cf < 16; ++cf) {
            const int f = cf * 16 + l16;
#pragma unroll
            for (int r = 0; r < 4; ++r) {
                const int brow = b0 + quad * 4 + r;
                const float cv = (float)ctx[((size_t)((brow * CI_ + i) * N_ + n)) * E_ + f];
                accf[cf][r] += cv * g[cf][r];
            }
        }
    }

    // epilogue: +bias +residual, LayerNorm over f (256), store f32
    const float bias_no = bias[n * CO_ + o];
#pragma unroll
    for (int r = 0; r < 4; ++r) {
        const int brow = b0 + quad * 4 + r;
        const float* resid = feat + ((size_t)((brow * N_ + n) * CI_ + o)) * E_;
        float s = 0.f;
#pragma unroll
        for (int cf = 0; cf < 16; ++cf) {
            const float v = accf[cf][r] + bias_no + resid[cf * 16 + l16];
            accf[cf][r] = v;
            s += v;
        }
#pragma unroll
        for (int m = 1; m < 16; m <<= 1) s += __shfl_xor(s, m);
        const float mean = s * (1.f / 256.f);
        float s2 = 0.f;
#pragma unroll
        for (int cf = 0; cf < 16; ++cf) {
            const float d = accf[cf][r] - mean;
            s2 += d * d;
        }
#pragma unroll
        for (int m = 1; m < 16; m <<= 1) s2 += __shfl_xor(s2, m);
        const float rstd = rsqrtf(s2 * (1.f / 256.f) + 1e-12f);
        float* op = out + ((size_t)((brow * N_ + n) * CO_ + o)) * E_;
#pragma unroll
        for (int cf = 0; cf < 16; ++cf) {
            const int f = cf * 16 + l16;
            op[f] = (accf[cf][r] - mean) * rstd * gamma[f] + beta[f];
        }
    }
}

// ---------------------------------------------------------------------------
extern "C" void kernel_launch(void* const* d_in, const int* in_sizes, int n_in,
                              void* d_out, int out_size, void* d_ws, size_t ws_size,
                              hipStream_t stream) {
    const float* feat = (const float*)d_in[0];
    const float* kern = (const float*)d_in[1];
    const float* bias = (const float*)d_in[2];
    const float* wq = (const float*)d_in[3];
    const float* bq = (const float*)d_in[4];
    const float* wk = (const float*)d_in[5];
    const float* bk = (const float*)d_in[6];
    const float* wv = (const float*)d_in[7];
    const float* bv = (const float*)d_in[8];
    const float* gamma = (const float*)d_in[9];
    const float* beta = (const float*)d_in[10];

    __bf16* ws = (__bf16*)d_ws;
    __bf16* wt = ws;                          // 3 * 65536
    __bf16* kt = wt + (size_t)3 * 65536;      // 96 * 65536
    __bf16* ctx = kt + (size_t)96 * 65536;    // 2048*24*256
    __bf16* gQ = ctx + (size_t)2048 * 24 * 256;
    __bf16* gK = gQ + (size_t)2048 * 24 * 256;
    __bf16* gVT = gK + (size_t)2048 * 24 * 256;  // [2048][256][24]
    float* out = (float*)d_out;

    hipLaunchKernelGGL(ktrans, dim3(99 * 16), dim3(256), 0, stream,
                       kern, wq, wk, wv, wt, kt);
    hipLaunchKernelGGL(kqkv, dim3(B_ * CI_), dim3(256), 0, stream,
                       feat, wt, bq, bk, bv, gQ, gK, gVT);
    hipLaunchKernelGGL(kattn2, dim3(B_ * CI_), dim3(256), 0, stream,
                       gQ, gK, gVT, ctx);
    hipLaunchKernelGGL(kpkln, dim3(16, N_, CO_), dim3(256), 0, stream,
                       feat, kt, ctx, bias, gamma, beta, out);
}

// Round 3
// 317.627 us; speedup vs baseline: 1.3239x; 1.2351x over previous
//
#include <hip/hip_runtime.h>

#define B_ 1024
#define N_ 24
#define CI_ 2
#define CO_ 2
#define E_ 256
#define H_ 4
#define DH_ 64
#define M_ (B_ * CI_ * N_)  // 49152 flattened rows, order m = (b*2+i)*24 + n

typedef __bf16 v8bf __attribute__((ext_vector_type(8)));
typedef float v4f __attribute__((ext_vector_type(4)));

union Frag {
    uint4 u;
    v8bf v;
};

union Pack4 {
    ushort4 u;
    __bf16 h[4];
};

__device__ __forceinline__ v4f mfma16(v8bf a, v8bf b, v4f c) {
    return __builtin_amdgcn_mfma_f32_16x16x32_bf16(a, b, c, 0, 0, 0);
}

// load 8 consecutive f32 and round to 8 bf16
__device__ __forceinline__ v8bf cvt8(const float* __restrict__ p) {
    float4 a = *(const float4*)p;
    float4 b = *(const float4*)(p + 4);
    v8bf r;
    r[0] = (__bf16)a.x; r[1] = (__bf16)a.y; r[2] = (__bf16)a.z; r[3] = (__bf16)a.w;
    r[4] = (__bf16)b.x; r[5] = (__bf16)b.y; r[6] = (__bf16)b.z; r[7] = (__bf16)b.w;
    return r;
}

// async global->LDS DMA, 16B per lane (dst is wave-uniform base + lane*16)
__device__ __forceinline__ void gload16(const __bf16* g, __bf16* l) {
    __builtin_amdgcn_global_load_lds(
        (const __attribute__((address_space(1))) unsigned int*)g,
        (__attribute__((address_space(3))) unsigned int*)l, 16, 0, 0);
}

// ---------------------------------------------------------------------------
// Kernel T: downcast f32->bf16 + transpose last-two-dims of kernel tensor
// (96 mats of 256x256) and Wq/Wk/Wv (3 mats) so MFMA B-fragments become
// contiguous 16B bf16 loads.
// ---------------------------------------------------------------------------
__global__ __launch_bounds__(256) void ktrans(
    const float* __restrict__ kern, const float* __restrict__ wq,
    const float* __restrict__ wk, const float* __restrict__ wv,
    __bf16* __restrict__ wt, __bf16* __restrict__ kt) {
    __shared__ __bf16 t[64][65];
    const int blk = blockIdx.x;
    const int mat = blk >> 4, tile = blk & 15;
    const int r0 = (tile >> 2) * 64, c0 = (tile & 3) * 64;
    const float* src;
    __bf16* dst;
    if (mat < 96) {
        src = kern + (size_t)mat * 65536;
        dst = kt + (size_t)mat * 65536;
    } else {
        int p = mat - 96;
        src = (p == 0) ? wq : (p == 1) ? wk : wv;
        dst = wt + (size_t)p * 65536;
    }
    const int tid = threadIdx.x;
#pragma unroll
    for (int k = 0; k < 16; ++k) {
        int idx = k * 256 + tid;
        int e = idx >> 6, f = idx & 63;
        t[f][e] = (__bf16)src[(size_t)(r0 + e) * 256 + c0 + f];
    }
    __syncthreads();
#pragma unroll
    for (int k = 0; k < 16; ++k) {
        int idx = k * 256 + tid;
        int f = idx >> 6, e = idx & 63;
        dst[(size_t)(c0 + f) * 256 + r0 + e] = t[f][e];
    }
}

// ---------------------------------------------------------------------------
// Kernel FB: feat f32 -> featb bf16, rows permuted to m = (b*2+i)*24 + n.
// Coalesced 16B writes; reads are 1KB-contiguous per source row.
// ---------------------------------------------------------------------------
__global__ __launch_bounds__(256) void kfeatb(
    const float* __restrict__ feat, __bf16* __restrict__ featb) {
    const int t = blockIdx.x * 256 + threadIdx.x;
    const int m = t >> 5;           // 32 threads per 256-elem row
    const int e0 = (t & 31) * 8;
    const int b = m / 48, r2 = m % 48;
    const int i = r2 / 24, n = r2 % 24;
    const float* src = feat + (((size_t)(b * 24 + n) * 2 + i) * 256 + e0);
    v8bf v = cvt8(src);
    *(v8bf*)(featb + ((size_t)m << 8) + e0) = v;
}

// ---------------------------------------------------------------------------
// Kernel QKV2: C[49152 x 768] = featb . [Wq|Wk|Wv]^T as a tiled GEMM.
// Grid (6, 384): x = col-block cb (2 per matrix), y = 128-row m-block.
// 512 thr = 8 waves (wave grid 4x2, each wave 32x64 of C). 2-phase K-loop,
// K_STEP=64 (4 steps), both tiles staged via global_load_lds (16B, linear LDS).
// cb 0..3 (Q,K): compute C^T (A=W-frags, B=feat-frags) so each lane holds 4
//   consecutive f -> packed 8B stores to gQ/gK[m][f].
// cb 4..5 (V): compute C normal so each lane holds 4 consecutive m (=4
//   consecutive n, since m-order is (b,i,n)) -> packed 8B stores to gVT[bs][f][n].
// ---------------------------------------------------------------------------
__global__ __launch_bounds__(512) void kqkv2(
    const __bf16* __restrict__ featb, const __bf16* __restrict__ wt,
    const float* __restrict__ bq, const float* __restrict__ bk,
    const float* __restrict__ bv,
    __bf16* __restrict__ gQ, __bf16* __restrict__ gK, __bf16* __restrict__ gVT) {
    __shared__ __bf16 sF[128 * 64];  // 16 KB feat tile [row][64k]
    __shared__ __bf16 sW[128 * 64];  // 16 KB weight tile [f][64k]

    const int cb = blockIdx.x;  // 0..5
    const int by = blockIdx.y;  // 0..383
    const int m0 = by * 128;
    const int m3 = cb >> 1;           // matrix: 0=Q 1=K 2=V
    const int f0 = (cb & 1) * 128;    // f-half
    const bool vpath = (cb >= 4);
    const int tid = threadIdx.x;
    const int w = tid >> 6, lane = tid & 63;
    const int quad = lane >> 4, l16 = lane & 15;
    const int wr = w >> 1, wc = w & 1;  // wave tile: rows wr*32, cols wc*64

    // staging: wave w stages rows [w*16, w*16+16) of both tiles
    const int srow = lane >> 3;  // 0..7 within 8-row chunk
    const int sslot = lane & 7;  // 16B slot within 128B row

    const v4f zf = {0.f, 0.f, 0.f, 0.f};
    v4f acc[2][4];
#pragma unroll
    for (int ri = 0; ri < 2; ++ri)
#pragma unroll
        for (int ci = 0; ci < 4; ++ci) acc[ri][ci] = zf;

#pragma unroll
    for (int s = 0; s < 4; ++s) {
        const int kb = s * 64;
#pragma unroll
        for (int j = 0; j < 2; ++j) {
            const int r = w * 16 + j * 8 + srow;
            gload16(featb + (((size_t)(m0 + r)) << 8) + kb + sslot * 8,
                    sF + (w * 16 + j * 8) * 64);
            gload16(wt + (((size_t)(m3 * 256 + f0 + r)) << 8) + kb + sslot * 8,
                    sW + (w * 16 + j * 8) * 64);
        }
        __syncthreads();  // drains vmcnt(0): DMA data visible

        const __bf16* As = vpath ? (const __bf16*)sF : (const __bf16*)sW;
        const __bf16* Bs = vpath ? (const __bf16*)sW : (const __bf16*)sF;
#pragma unroll
        for (int kk = 0; kk < 64; kk += 32) {
            Frag fa[2], fb[4];
#pragma unroll
            for (int ri = 0; ri < 2; ++ri)
                fa[ri].u = *(const uint4*)(As + (wr * 32 + ri * 16 + l16) * 64 + kk + quad * 8);
#pragma unroll
            for (int ci = 0; ci < 4; ++ci)
                fb[ci].u = *(const uint4*)(Bs + (wc * 64 + ci * 16 + l16) * 64 + kk + quad * 8);
#pragma unroll
            for (int ri = 0; ri < 2; ++ri)
#pragma unroll
                for (int ci = 0; ci < 4; ++ci)
                    acc[ri][ci] = mfma16(fa[ri].v, fb[ci].v, acc[ri][ci]);
        }
        __syncthreads();  // protect LDS before next stage
    }

    if (!vpath) {
        // C^T: row = f, col = m. Lane holds 4 consecutive f at one m.
        __bf16* dst = (cb < 2) ? gQ : gK;
        const float* bvec = (cb < 2) ? bq : bk;
#pragma unroll
        for (int ri = 0; ri < 2; ++ri) {
            const int fg0 = f0 + wr * 32 + ri * 16 + quad * 4;
            const float4 b4 = *(const float4*)(bvec + fg0);
#pragma unroll
            for (int ci = 0; ci < 4; ++ci) {
                const int mg = m0 + wc * 64 + ci * 16 + l16;
                Pack4 p;
                p.h[0] = (__bf16)(acc[ri][ci][0] + b4.x);
                p.h[1] = (__bf16)(acc[ri][ci][1] + b4.y);
                p.h[2] = (__bf16)(acc[ri][ci][2] + b4.z);
                p.h[3] = (__bf16)(acc[ri][ci][3] + b4.w);
                *(ushort4*)(dst + (((size_t)mg) << 8) + fg0) = p.u;
            }
        }
    } else {
        // C normal: row = m, col = f. Lane holds 4 consecutive m = 4 consecutive n.
#pragma unroll
        for (int ri = 0; ri < 2; ++ri) {
            const int mg0 = m0 + wr * 32 + ri * 16 + quad * 4;
            const int bs = mg0 / 24, n0 = mg0 % 24;
#pragma unroll
            for (int ci = 0; ci < 4; ++ci) {
                const int fg = f0 + wc * 64 + ci * 16 + l16;
                const float bvf = bv[fg];
                Pack4 p;
                p.h[0] = (__bf16)(acc[ri][ci][0] + bvf);
                p.h[1] = (__bf16)(acc[ri][ci][1] + bvf);
                p.h[2] = (__bf16)(acc[ri][ci][2] + bvf);
                p.h[3] = (__bf16)(acc[ri][ci][3] + bvf);
                *(ushort4*)(gVT + ((size_t)bs * 256 + fg) * 24 + n0) = p.u;
            }
        }
    }
}

// ---------------------------------------------------------------------------
// Kernel A2: scores + softmax + PV. One (b,seq) per block, wave = head.
// No __syncthreads: the only LDS (P staging) is wave-local.
// ---------------------------------------------------------------------------
__global__ __launch_bounds__(256) void kattn2(
    const __bf16* __restrict__ gQ, const __bf16* __restrict__ gK,
    const __bf16* __restrict__ gVT, __bf16* __restrict__ ctx) {
    __shared__ __bf16 sP[H_][N_][56];  // 10.5 KB, wave-local rows

    const int bs = blockIdx.x;  // 0..2047
    const int tid = threadIdx.x;
    const int h = tid >> 6, lane = tid & 63;
    const int quad = lane >> 4, l16 = lane & 15;

    const uint4 zero4 = make_uint4(0u, 0u, 0u, 0u);
    const v4f zf = {0.f, 0.f, 0.f, 0.f};

    // ---- scores = Q K^T / 8 ----
    v4f sc[2][2];
#pragma unroll
    for (int mt = 0; mt < 2; ++mt)
#pragma unroll
        for (int nt = 0; nt < 2; ++nt) sc[mt][nt] = zf;

#pragma unroll
    for (int ks = 0; ks < 2; ++ks) {
        const int d0 = h * DH_ + ks * 32 + quad * 8;
        Frag a[2], bb[2];
#pragma unroll
        for (int mt = 0; mt < 2; ++mt) {
            const int qn = mt * 16 + l16;
            a[mt].u = (qn < N_) ? *(const uint4*)(gQ + (size_t)(bs * N_ + qn) * E_ + d0) : zero4;
        }
#pragma unroll
        for (int nt = 0; nt < 2; ++nt) {
            const int kn = nt * 16 + l16;
            bb[nt].u = (kn < N_) ? *(const uint4*)(gK + (size_t)(bs * N_ + kn) * E_ + d0) : zero4;
        }
#pragma unroll
        for (int mt = 0; mt < 2; ++mt)
#pragma unroll
            for (int nt = 0; nt < 2; ++nt)
                sc[mt][nt] = mfma16(a[mt].v, bb[nt].v, sc[mt][nt]);
    }

    // ---- softmax (rows in-register, 16-lane shuffles) ----
    const float scale = 0.125f;  // 1/sqrt(64)
#pragma unroll
    for (int mt = 0; mt < 2; ++mt) {
#pragma unroll
        for (int r = 0; r < 4; ++r) {
            const int qn = mt * 16 + quad * 4 + r;
            const float v0 = sc[mt][0][r] * scale;
            const float v1 = (l16 < 8) ? sc[mt][1][r] * scale : -3.0e38f;  // kn>=24 masked
            float mx = fmaxf(v0, v1);
#pragma unroll
            for (int m = 1; m < 16; m <<= 1) mx = fmaxf(mx, __shfl_xor(mx, m));
            const float e0 = __expf(v0 - mx);
            const float e1 = (l16 < 8) ? __expf(v1 - mx) : 0.f;
            float s = e0 + e1;
#pragma unroll
            for (int m = 1; m < 16; m <<= 1) s += __shfl_xor(s, m);
            const float inv = 1.f / s;
            if (qn < N_) {
                sP[h][qn][l16] = (__bf16)(e0 * inv);
                sP[h][qn][16 + l16] = (__bf16)(e1 * inv);
            }
        }
    }
    // no barrier: sP[h] is wave-local; compiler inserts lgkmcnt waits

    // ---- ctx = P @ V ----
    Frag pa[2], vb[4];
#pragma unroll
    for (int mt = 0; mt < 2; ++mt) {
        const int qn = mt * 16 + l16;
        pa[mt].u = (qn < N_) ? *(const uint4*)(&sP[h][qn][quad * 8]) : zero4;
    }
#pragma unroll
    for (int nt = 0; nt < 4; ++nt) {
        const int f = h * DH_ + nt * 16 + l16;
        vb[nt].u = (quad < 3) ? *(const uint4*)(gVT + (size_t)(bs * E_ + f) * N_ + quad * 8) : zero4;
    }
#pragma unroll
    for (int mt = 0; mt < 2; ++mt) {
#pragma unroll
        for (int nt = 0; nt < 4; ++nt) {
            v4f c0 = zf;
            c0 = mfma16(pa[mt].v, vb[nt].v, c0);
#pragma unroll
            for (int r = 0; r < 4; ++r) {
                const int qn = mt * 16 + quad * 4 + r;
                if (qn < N_) {
                    const int f = h * DH_ + nt * 16 + l16;
                    ctx[((size_t)(bs * N_ + qn)) * E_ + f] = (__bf16)c0[r];
                }
            }
        }
    }
}

// ---------------------------------------------------------------------------
// Kernel P: pkq[b,n,o,f] = sum_i ctx[b,i,n,f] * (feat[b,n,i,:] @ K[o,i,n,:,f])
//           + bias + residual, then LayerNorm over f.
// A-fragments now loaded directly from featb (bf16, no cvt).
// ---------------------------------------------------------------------------
__global__ __launch_bounds__(256) void kpkln(
    const float* __restrict__ feat, const __bf16* __restrict__ featb,
    const __bf16* __restrict__ kt, const __bf16* __restrict__ ctx,
    const float* __restrict__ bias, const float* __restrict__ gamma,
    const float* __restrict__ beta, float* __restrict__ out) {
    const int bt = blockIdx.x;  // 0..15
    const int n = blockIdx.y;   // 0..23
    const int o = blockIdx.z;   // 0..1
    const int tid = threadIdx.x;
    const int wave = tid >> 6, lane = tid & 63;
    const int quad = lane >> 4, l16 = lane & 15;
    const int b0 = bt * 64 + wave * 16;

    const v4f zf = {0.f, 0.f, 0.f, 0.f};
    float accf[16][4];
#pragma unroll
    for (int cf = 0; cf < 16; ++cf)
#pragma unroll
        for (int r = 0; r < 4; ++r) accf[cf][r] = 0.f;

#pragma unroll
    for (int i = 0; i < CI_; ++i) {
        v4f g[16];
#pragma unroll
        for (int cf = 0; cf < 16; ++cf) g[cf] = zf;

        // featb row for (b = b0+l16, i, n): m = ((b*2)+i)*24 + n
        const __bf16* A = featb + (((size_t)((b0 + l16) * 2 + i) * 24 + n) << 8);
        const __bf16* Bm = kt + ((size_t)((o * CI_ + i) * N_ + n)) * 65536;
#pragma unroll
        for (int ks = 0; ks < 8; ++ks) {
            const int kb = ks * 32 + quad * 8;
            Frag a;
            a.u = *(const uint4*)(A + kb);
#pragma unroll
            for (int cf = 0; cf < 16; ++cf) {
                Frag bb;
                bb.u = *(const uint4*)(Bm + (size_t)(cf * 16 + l16) * E_ + kb);
                g[cf] = mfma16(a.v, bb.v, g[cf]);
            }
        }
        // scale by ctx and accumulate over i
#pragma unroll
        for (int cf = 0; cf < 16; ++cf) {
            const int f = cf * 16 + l16;
#pragma unroll
            for (int r = 0; r < 4; ++r) {
                const int brow = b0 + quad * 4 + r;
                const float cv = (float)ctx[((size_t)((brow * CI_ + i) * N_ + n)) * E_ + f];
                accf[cf][r] += cv * g[cf][r];
            }
        }
    }

    // epilogue: +bias +residual, LayerNorm over f (256), store f32
    const float bias_no = bias[n * CO_ + o];
#pragma unroll
    for (int r = 0; r < 4; ++r) {
        const int brow = b0 + quad * 4 + r;
        const float* resid = feat + ((size_t)((brow * N_ + n) * CI_ + o)) * E_;
        float s = 0.f;
#pragma unroll
        for (int cf = 0; cf < 16; ++cf) {
            const float v = accf[cf][r] + bias_no + resid[cf * 16 + l16];
            accf[cf][r] = v;
            s += v;
        }
#pragma unroll
        for (int m = 1; m < 16; m <<= 1) s += __shfl_xor(s, m);
        const float mean = s * (1.f / 256.f);
        float s2 = 0.f;
#pragma unroll
        for (int cf = 0; cf < 16; ++cf) {
            const float d = accf[cf][r] - mean;
            s2 += d * d;
        }
#pragma unroll
        for (int m = 1; m < 16; m <<= 1) s2 += __shfl_xor(s2, m);
        const float rstd = rsqrtf(s2 * (1.f / 256.f) + 1e-12f);
        float* op = out + ((size_t)((brow * N_ + n) * CO_ + o)) * E_;
#pragma unroll
        for (int cf = 0; cf < 16; ++cf) {
            const int f = cf * 16 + l16;
            op[f] = (accf[cf][r] - mean) * rstd * gamma[f] + beta[f];
        }
    }
}

// ---------------------------------------------------------------------------
extern "C" void kernel_launch(void* const* d_in, const int* in_sizes, int n_in,
                              void* d_out, int out_size, void* d_ws, size_t ws_size,
                              hipStream_t stream) {
    const float* feat = (const float*)d_in[0];
    const float* kern = (const float*)d_in[1];
    const float* bias = (const float*)d_in[2];
    const float* wq = (const float*)d_in[3];
    const float* bq = (const float*)d_in[4];
    const float* wk = (const float*)d_in[5];
    const float* bk = (const float*)d_in[6];
    const float* wv = (const float*)d_in[7];
    const float* bv = (const float*)d_in[8];
    const float* gamma = (const float*)d_in[9];
    const float* beta = (const float*)d_in[10];

    __bf16* ws = (__bf16*)d_ws;
    __bf16* wt = ws;                              // 3 * 65536
    __bf16* kt = wt + (size_t)3 * 65536;          // 96 * 65536
    __bf16* ctx = kt + (size_t)96 * 65536;        // 2048*24*256
    __bf16* gQ = ctx + (size_t)2048 * 24 * 256;   // [49152][256]
    __bf16* gK = gQ + (size_t)M_ * 256;           // [49152][256]
    __bf16* gVT = gK + (size_t)M_ * 256;          // [2048][256][24]
    __bf16* featb = gVT + (size_t)2048 * 256 * 24;  // [49152][256]
    float* out = (float*)d_out;

    hipLaunchKernelGGL(ktrans, dim3(99 * 16), dim3(256), 0, stream,
                       kern, wq, wk, wv, wt, kt);
    hipLaunchKernelGGL(kfeatb, dim3(M_ * 32 / 256), dim3(256), 0, stream,
                       feat, featb);
    hipLaunchKernelGGL(kqkv2, dim3(6, 384), dim3(512), 0, stream,
                       featb, wt, bq, bk, bv, gQ, gK, gVT);
    hipLaunchKernelGGL(kattn2, dim3(B_ * CI_), dim3(256), 0, stream,
                       gQ, gK, gVT, ctx);
    hipLaunchKernelGGL(kpkln, dim3(16, N_, CO_), dim3(256), 0, stream,
                       feat, featb, kt, ctx, bias, gamma, beta, out);
}

// Round 5
// 263.937 us; speedup vs baseline: 1.5932x; 1.2034x over previous
//
#include <hip/hip_runtime.h>

#define B_ 1024
#define N_ 24
#define CI_ 2
#define CO_ 2
#define E_ 256
#define H_ 4
#define DH_ 64
#define M_ (B_ * CI_ * N_)  // 49152 flattened rows, order m = (b*2+i)*24 + n

typedef __bf16 v8bf __attribute__((ext_vector_type(8)));
typedef float v4f __attribute__((ext_vector_type(4)));

union Frag {
    uint4 u;
    v8bf v;
};

union Pack4 {
    ushort4 u;
    __bf16 h[4];
};

__device__ __forceinline__ v4f mfma16(v8bf a, v8bf b, v4f c) {
    return __builtin_amdgcn_mfma_f32_16x16x32_bf16(a, b, c, 0, 0, 0);
}

// load 8 consecutive f32 and round to 8 bf16
__device__ __forceinline__ v8bf cvt8(const float* __restrict__ p) {
    float4 a = *(const float4*)p;
    float4 b = *(const float4*)(p + 4);
    v8bf r;
    r[0] = (__bf16)a.x; r[1] = (__bf16)a.y; r[2] = (__bf16)a.z; r[3] = (__bf16)a.w;
    r[4] = (__bf16)b.x; r[5] = (__bf16)b.y; r[6] = (__bf16)b.z; r[7] = (__bf16)b.w;
    return r;
}

// async global->LDS DMA, 16B per lane (dst is wave-uniform base + lane*16)
__device__ __forceinline__ void gload16(const __bf16* g, __bf16* l) {
    __builtin_amdgcn_global_load_lds(
        (const __attribute__((address_space(1))) unsigned int*)g,
        (__attribute__((address_space(3))) unsigned int*)l, 16, 0, 0);
}

// ---------------------------------------------------------------------------
// Kernel T: downcast f32->bf16 + transpose last-two-dims of kernel tensor
// (96 mats of 256x256) and Wq/Wk/Wv (3 mats) so MFMA B-fragments become
// contiguous 16B bf16 loads.
// ---------------------------------------------------------------------------
__global__ __launch_bounds__(256) void ktrans(
    const float* __restrict__ kern, const float* __restrict__ wq,
    const float* __restrict__ wk, const float* __restrict__ wv,
    __bf16* __restrict__ wt, __bf16* __restrict__ kt) {
    __shared__ __bf16 t[64][65];
    const int blk = blockIdx.x;
    const int mat = blk >> 4, tile = blk & 15;
    const int r0 = (tile >> 2) * 64, c0 = (tile & 3) * 64;
    const float* src;
    __bf16* dst;
    if (mat < 96) {
        src = kern + (size_t)mat * 65536;
        dst = kt + (size_t)mat * 65536;
    } else {
        int p = mat - 96;
        src = (p == 0) ? wq : (p == 1) ? wk : wv;
        dst = wt + (size_t)p * 65536;
    }
    const int tid = threadIdx.x;
#pragma unroll
    for (int k = 0; k < 16; ++k) {
        int idx = k * 256 + tid;
        int e = idx >> 6, f = idx & 63;
        t[f][e] = (__bf16)src[(size_t)(r0 + e) * 256 + c0 + f];
    }
    __syncthreads();
#pragma unroll
    for (int k = 0; k < 16; ++k) {
        int idx = k * 256 + tid;
        int f = idx >> 6, e = idx & 63;
        dst[(size_t)(c0 + f) * 256 + r0 + e] = t[f][e];
    }
}

// ---------------------------------------------------------------------------
// Kernel FB: feat f32 -> featb bf16, rows permuted to m = (b*2+i)*24 + n.
// ---------------------------------------------------------------------------
__global__ __launch_bounds__(256) void kfeatb(
    const float* __restrict__ feat, __bf16* __restrict__ featb) {
    const int t = blockIdx.x * 256 + threadIdx.x;
    const int m = t >> 5;           // 32 threads per 256-elem row
    const int e0 = (t & 31) * 8;
    const int b = m / 48, r2 = m % 48;
    const int i = r2 / 24, n = r2 % 24;
    const float* src = feat + (((size_t)(b * 24 + n) * 2 + i) * 256 + e0);
    v8bf v = cvt8(src);
    *(v8bf*)(featb + ((size_t)m << 8) + e0) = v;
}

// ---------------------------------------------------------------------------
// Kernel QKV2: C[49152 x 768] = featb . [Wq|Wk|Wv]^T as a tiled GEMM.
// (unchanged — verified working in round 3)
// ---------------------------------------------------------------------------
__global__ __launch_bounds__(512) void kqkv2(
    const __bf16* __restrict__ featb, const __bf16* __restrict__ wt,
    const float* __restrict__ bq, const float* __restrict__ bk,
    const float* __restrict__ bv,
    __bf16* __restrict__ gQ, __bf16* __restrict__ gK, __bf16* __restrict__ gVT) {
    __shared__ __bf16 sF[128 * 64];  // 16 KB feat tile [row][64k]
    __shared__ __bf16 sW[128 * 64];  // 16 KB weight tile [f][64k]

    const int cb = blockIdx.x;  // 0..5
    const int by = blockIdx.y;  // 0..383
    const int m0 = by * 128;
    const int m3 = cb >> 1;           // matrix: 0=Q 1=K 2=V
    const int f0 = (cb & 1) * 128;    // f-half
    const bool vpath = (cb >= 4);
    const int tid = threadIdx.x;
    const int w = tid >> 6, lane = tid & 63;
    const int quad = lane >> 4, l16 = lane & 15;
    const int wr = w >> 1, wc = w & 1;  // wave tile: rows wr*32, cols wc*64

    const int srow = lane >> 3;  // 0..7 within 8-row chunk
    const int sslot = lane & 7;  // 16B slot within 128B row

    const v4f zf = {0.f, 0.f, 0.f, 0.f};
    v4f acc[2][4];
#pragma unroll
    for (int ri = 0; ri < 2; ++ri)
#pragma unroll
        for (int ci = 0; ci < 4; ++ci) acc[ri][ci] = zf;

#pragma unroll
    for (int s = 0; s < 4; ++s) {
        const int kb = s * 64;
#pragma unroll
        for (int j = 0; j < 2; ++j) {
            const int r = w * 16 + j * 8 + srow;
            gload16(featb + (((size_t)(m0 + r)) << 8) + kb + sslot * 8,
                    sF + (w * 16 + j * 8) * 64);
            gload16(wt + (((size_t)(m3 * 256 + f0 + r)) << 8) + kb + sslot * 8,
                    sW + (w * 16 + j * 8) * 64);
        }
        __syncthreads();

        const __bf16* As = vpath ? (const __bf16*)sF : (const __bf16*)sW;
        const __bf16* Bs = vpath ? (const __bf16*)sW : (const __bf16*)sF;
#pragma unroll
        for (int kk = 0; kk < 64; kk += 32) {
            Frag fa[2], fb[4];
#pragma unroll
            for (int ri = 0; ri < 2; ++ri)
                fa[ri].u = *(const uint4*)(As + (wr * 32 + ri * 16 + l16) * 64 + kk + quad * 8);
#pragma unroll
            for (int ci = 0; ci < 4; ++ci)
                fb[ci].u = *(const uint4*)(Bs + (wc * 64 + ci * 16 + l16) * 64 + kk + quad * 8);
#pragma unroll
            for (int ri = 0; ri < 2; ++ri)
#pragma unroll
                for (int ci = 0; ci < 4; ++ci)
                    acc[ri][ci] = mfma16(fa[ri].v, fb[ci].v, acc[ri][ci]);
        }
        __syncthreads();
    }

    if (!vpath) {
        __bf16* dst = (cb < 2) ? gQ : gK;
        const float* bvec = (cb < 2) ? bq : bk;
#pragma unroll
        for (int ri = 0; ri < 2; ++ri) {
            const int fg0 = f0 + wr * 32 + ri * 16 + quad * 4;
            const float4 b4 = *(const float4*)(bvec + fg0);
#pragma unroll
            for (int ci = 0; ci < 4; ++ci) {
                const int mg = m0 + wc * 64 + ci * 16 + l16;
                Pack4 p;
                p.h[0] = (__bf16)(acc[ri][ci][0] + b4.x);
                p.h[1] = (__bf16)(acc[ri][ci][1] + b4.y);
                p.h[2] = (__bf16)(acc[ri][ci][2] + b4.z);
                p.h[3] = (__bf16)(acc[ri][ci][3] + b4.w);
                *(ushort4*)(dst + (((size_t)mg) << 8) + fg0) = p.u;
            }
        }
    } else {
#pragma unroll
        for (int ri = 0; ri < 2; ++ri) {
            const int mg0 = m0 + wr * 32 + ri * 16 + quad * 4;
            const int bs = mg0 / 24, n0 = mg0 % 24;
#pragma unroll
            for (int ci = 0; ci < 4; ++ci) {
                const int fg = f0 + wc * 64 + ci * 16 + l16;
                const float bvf = bv[fg];
                Pack4 p;
                p.h[0] = (__bf16)(acc[ri][ci][0] + bvf);
                p.h[1] = (__bf16)(acc[ri][ci][1] + bvf);
                p.h[2] = (__bf16)(acc[ri][ci][2] + bvf);
                p.h[3] = (__bf16)(acc[ri][ci][3] + bvf);
                *(ushort4*)(gVT + ((size_t)bs * 256 + fg) * 24 + n0) = p.u;
            }
        }
    }
}

// ---------------------------------------------------------------------------
// Kernel A2: scores + softmax + PV. One (b,seq) per block, wave = head.
// (unchanged — verified working in round 3)
// ---------------------------------------------------------------------------
__global__ __launch_bounds__(256) void kattn2(
    const __bf16* __restrict__ gQ, const __bf16* __restrict__ gK,
    const __bf16* __restrict__ gVT, __bf16* __restrict__ ctx) {
    __shared__ __bf16 sP[H_][N_][56];  // 10.5 KB, wave-local rows

    const int bs = blockIdx.x;  // 0..2047
    const int tid = threadIdx.x;
    const int h = tid >> 6, lane = tid & 63;
    const int quad = lane >> 4, l16 = lane & 15;

    const uint4 zero4 = make_uint4(0u, 0u, 0u, 0u);
    const v4f zf = {0.f, 0.f, 0.f, 0.f};

    v4f sc[2][2];
#pragma unroll
    for (int mt = 0; mt < 2; ++mt)
#pragma unroll
        for (int nt = 0; nt < 2; ++nt) sc[mt][nt] = zf;

#pragma unroll
    for (int ks = 0; ks < 2; ++ks) {
        const int d0 = h * DH_ + ks * 32 + quad * 8;
        Frag a[2], bb[2];
#pragma unroll
        for (int mt = 0; mt < 2; ++mt) {
            const int qn = mt * 16 + l16;
            a[mt].u = (qn < N_) ? *(const uint4*)(gQ + (size_t)(bs * N_ + qn) * E_ + d0) : zero4;
        }
#pragma unroll
        for (int nt = 0; nt < 2; ++nt) {
            const int kn = nt * 16 + l16;
            bb[nt].u = (kn < N_) ? *(const uint4*)(gK + (size_t)(bs * N_ + kn) * E_ + d0) : zero4;
        }
#pragma unroll
        for (int mt = 0; mt < 2; ++mt)
#pragma unroll
            for (int nt = 0; nt < 2; ++nt)
                sc[mt][nt] = mfma16(a[mt].v, bb[nt].v, sc[mt][nt]);
    }

    const float scale = 0.125f;  // 1/sqrt(64)
#pragma unroll
    for (int mt = 0; mt < 2; ++mt) {
#pragma unroll
        for (int r = 0; r < 4; ++r) {
            const int qn = mt * 16 + quad * 4 + r;
            const float v0 = sc[mt][0][r] * scale;
            const float v1 = (l16 < 8) ? sc[mt][1][r] * scale : -3.0e38f;  // kn>=24 masked
            float mx = fmaxf(v0, v1);
#pragma unroll
            for (int m = 1; m < 16; m <<= 1) mx = fmaxf(mx, __shfl_xor(mx, m));
            const float e0 = __expf(v0 - mx);
            const float e1 = (l16 < 8) ? __expf(v1 - mx) : 0.f;
            float s = e0 + e1;
#pragma unroll
            for (int m = 1; m < 16; m <<= 1) s += __shfl_xor(s, m);
            const float inv = 1.f / s;
            if (qn < N_) {
                sP[h][qn][l16] = (__bf16)(e0 * inv);
                sP[h][qn][16 + l16] = (__bf16)(e1 * inv);
            }
        }
    }
    // no barrier: sP[h] is wave-local

    Frag pa[2], vb[4];
#pragma unroll
    for (int mt = 0; mt < 2; ++mt) {
        const int qn = mt * 16 + l16;
        pa[mt].u = (qn < N_) ? *(const uint4*)(&sP[h][qn][quad * 8]) : zero4;
    }
#pragma unroll
    for (int nt = 0; nt < 4; ++nt) {
        const int f = h * DH_ + nt * 16 + l16;
        vb[nt].u = (quad < 3) ? *(const uint4*)(gVT + (size_t)(bs * E_ + f) * N_ + quad * 8) : zero4;
    }
#pragma unroll
    for (int mt = 0; mt < 2; ++mt) {
#pragma unroll
        for (int nt = 0; nt < 4; ++nt) {
            v4f c0 = zf;
            c0 = mfma16(pa[mt].v, vb[nt].v, c0);
#pragma unroll
            for (int r = 0; r < 4; ++r) {
                const int qn = mt * 16 + quad * 4 + r;
                if (qn < N_) {
                    const int f = h * DH_ + nt * 16 + l16;
                    ctx[((size_t)(bs * N_ + qn)) * E_ + f] = (__bf16)c0[r];
                }
            }
        }
    }
}

// ---------------------------------------------------------------------------
// Kernel P2: tiled-GEMM rewrite of kpkln (identical resubmit of round 4 —
// audited: all accesses in-bounds, DMA bases wave-uniform, layouts verified).
// Block = (n, o, 64 b-rows); 256 thr = 4 waves; wave = 16 b-rows x all 256 f.
// C^T orientation so each lane holds 4 consecutive f; LayerNorm wave-local.
// ---------------------------------------------------------------------------
__global__ __launch_bounds__(256) void kpkln2(
    const float* __restrict__ feat, const __bf16* __restrict__ featb,
    const __bf16* __restrict__ kt, const __bf16* __restrict__ ctx,
    const float* __restrict__ bias, const float* __restrict__ gamma,
    const float* __restrict__ beta, float* __restrict__ out) {
    __shared__ __bf16 sA[256 * 32];  // kt slice [f][32e], 16 KB
    __shared__ __bf16 sB[64 * 32];   // featb slice [b][32e], 4 KB

    const int id = blockIdx.x;
    const int n = id % 24;
    const int t2 = id / 24;   // 0..31
    const int o = t2 >> 4, bt = t2 & 15;
    const int tid = threadIdx.x;
    const int w = tid >> 6, lane = tid & 63;
    const int quad = lane >> 4, l16 = lane & 15;
    const int b0 = bt * 64;
    const int brow = b0 + w * 16 + l16;  // this lane's b row (C^T col)

    const v4f zf = {0.f, 0.f, 0.f, 0.f};
    float accf[16][4];
#pragma unroll
    for (int fi = 0; fi < 16; ++fi)
#pragma unroll
        for (int r = 0; r < 4; ++r) accf[fi][r] = 0.f;

#pragma unroll
    for (int i = 0; i < CI_; ++i) {
        const __bf16* Am = kt + ((size_t)((o * CI_ + i) * N_ + n)) * 65536;
        v4f g[16];
#pragma unroll
        for (int fi = 0; fi < 16; ++fi) g[fi] = zf;

#pragma unroll
        for (int ks = 0; ks < 8; ++ks) {
            const int kb = ks * 32;
            // stage kt slice: 16 KB = 16 wave-segments of 1 KB
#pragma unroll
            for (int j = 0; j < 4; ++j) {
                const int s = w * 4 + j;              // 0..15
                const int row = s * 16 + (lane >> 2);  // f row 0..255
                gload16(Am + (size_t)row * 256 + kb + (lane & 3) * 8,
                        sA + s * 512);
            }
            // stage featb slice: 4 KB = 4 wave-segments of 1 KB
            {
                const int row = w * 16 + (lane >> 2);  // b row 0..63
                const size_t m = ((size_t)(b0 + row) * 2 + i) * 24 + n;
                gload16(featb + (m << 8) + kb + (lane & 3) * 8,
                        sB + w * 512);
            }
            __syncthreads();  // drain DMA, make tiles visible

            Frag bfrag;
            bfrag.u = *(const uint4*)(sB + (w * 16 + l16) * 32 + quad * 8);
#pragma unroll
            for (int fi = 0; fi < 16; ++fi) {
                Frag afrag;
                afrag.u = *(const uint4*)(sA + (fi * 16 + l16) * 32 + quad * 8);
                g[fi] = mfma16(afrag.v, bfrag.v, g[fi]);
            }
            __syncthreads();  // protect LDS before next stage
        }

        // scale by ctx (packed ushort4: 4 consecutive f per lane) and accumulate
        const __bf16* cr = ctx + (((size_t)((brow * 2 + i) * 24 + n)) << 8) + quad * 4;
#pragma unroll
        for (int fi = 0; fi < 16; ++fi) {
            Pack4 p;
            p.u = *(const ushort4*)(cr + fi * 16);
#pragma unroll
            for (int r = 0; r < 4; ++r)
                accf[fi][r] += (float)p.h[r] * g[fi][r];
        }
    }

    // epilogue: +bias +residual, LayerNorm over f (256), store f32
    const float bias_no = bias[n * CO_ + o];
    const float* resid = feat + (((size_t)((brow * 24 + n) * 2 + o)) << 8) + quad * 4;
    float s = 0.f;
#pragma unroll
    for (int fi = 0; fi < 16; ++fi) {
        const float4 rv = *(const float4*)(resid + fi * 16);
        accf[fi][0] += bias_no + rv.x;
        accf[fi][1] += bias_no + rv.y;
        accf[fi][2] += bias_no + rv.z;
        accf[fi][3] += bias_no + rv.w;
#pragma unroll
        for (int r = 0; r < 4; ++r) s += accf[fi][r];
    }
    // cross-quad reduce (lanes same l16, quads 0..3): lane bits 4,5
    s += __shfl_xor(s, 16);
    s += __shfl_xor(s, 32);
    const float mean = s * (1.f / 256.f);
    float s2 = 0.f;
#pragma unroll
    for (int fi = 0; fi < 16; ++fi)
#pragma unroll
        for (int r = 0; r < 4; ++r) {
            const float d = accf[fi][r] - mean;
            s2 += d * d;
        }
    s2 += __shfl_xor(s2, 16);
    s2 += __shfl_xor(s2, 32);
    const float rstd = rsqrtf(s2 * (1.f / 256.f) + 1e-12f);

    float* op = out + (((size_t)((brow * 24 + n) * 2 + o)) << 8) + quad * 4;
#pragma unroll
    for (int fi = 0; fi < 16; ++fi) {
        const int f = fi * 16 + quad * 4;
        const float4 gm = *(const float4*)(gamma + f);
        const float4 bt4 = *(const float4*)(beta + f);
        float4 ov;
        ov.x = (accf[fi][0] - mean) * rstd * gm.x + bt4.x;
        ov.y = (accf[fi][1] - mean) * rstd * gm.y + bt4.y;
        ov.z = (accf[fi][2] - mean) * rstd * gm.z + bt4.z;
        ov.w = (accf[fi][3] - mean) * rstd * gm.w + bt4.w;
        *(float4*)(op + fi * 16) = ov;
    }
}

// ---------------------------------------------------------------------------
extern "C" void kernel_launch(void* const* d_in, const int* in_sizes, int n_in,
                              void* d_out, int out_size, void* d_ws, size_t ws_size,
                              hipStream_t stream) {
    const float* feat = (const float*)d_in[0];
    const float* kern = (const float*)d_in[1];
    const float* bias = (const float*)d_in[2];
    const float* wq = (const float*)d_in[3];
    const float* bq = (const float*)d_in[4];
    const float* wk = (const float*)d_in[5];
    const float* bk = (const float*)d_in[6];
    const float* wv = (const float*)d_in[7];
    const float* bv = (const float*)d_in[8];
    const float* gamma = (const float*)d_in[9];
    const float* beta = (const float*)d_in[10];

    __bf16* ws = (__bf16*)d_ws;
    __bf16* wt = ws;                              // 3 * 65536
    __bf16* kt = wt + (size_t)3 * 65536;          // 96 * 65536
    __bf16* ctx = kt + (size_t)96 * 65536;        // [2048][24][256]
    __bf16* gQ = ctx + (size_t)2048 * 24 * 256;   // [49152][256]
    __bf16* gK = gQ + (size_t)M_ * 256;           // [49152][256]
    __bf16* gVT = gK + (size_t)M_ * 256;          // [2048][256][24]
    __bf16* featb = gVT + (size_t)2048 * 256 * 24;  // [49152][256]
    float* out = (float*)d_out;

    hipLaunchKernelGGL(ktrans, dim3(99 * 16), dim3(256), 0, stream,
                       kern, wq, wk, wv, wt, kt);
    hipLaunchKernelGGL(kfeatb, dim3(M_ * 32 / 256), dim3(256), 0, stream,
                       feat, featb);
    hipLaunchKernelGGL(kqkv2, dim3(6, 384), dim3(512), 0, stream,
                       featb, wt, bq, bk, bv, gQ, gK, gVT);
    hipLaunchKernelGGL(kattn2, dim3(B_ * CI_), dim3(256), 0, stream,
                       gQ, gK, gVT, ctx);
    hipLaunchKernelGGL(kpkln2, dim3(24 * 32), dim3(256), 0, stream,
                       feat, featb, kt, ctx, bias, gamma, beta, out);
}